// Round 13
// baseline (162.409 us; speedup 1.0000x reference)
//
#include <hip/hip_runtime.h>

#define N_NODES 100000
#define C_DIM   128
#define E_EDGES 1600000

// clang native vector types (accepted by __builtin_nontemporal_*).
typedef int   i4 __attribute__((ext_vector_type(4)));
typedef float f4 __attribute__((ext_vector_type(4)));

// Node-score tables in device globals (800 KB) — no ws_size assumption.
// Fully rewritten by node_dots_kernel every call before edge_fused_kernel
// reads them (same-stream ordering) — no cross-call state dependence.
__device__ float g_s_row[N_NODES];
__device__ float g_s_col[N_NODES];

// ---------------------------------------------------------------------------
// Kernel A: per-node dot products with w_row (W[0:128]) and w_col (W[128:256]).
// 32 lanes per node, float4 per lane -> one coalesced 512B segment per node.
// 256 threads/block => 8 nodes/block. N=100000 -> 12500 blocks exactly.
// ---------------------------------------------------------------------------
__global__ void node_dots_kernel(const float* __restrict__ x,
                                 const float* __restrict__ W) {
    const int lane = threadIdx.x & 31;        // 0..31 within node
    const int node = blockIdx.x * 8 + (threadIdx.x >> 5);
    if (node >= N_NODES) return;

    const f4 xv = *reinterpret_cast<const f4*>(x + (size_t)node * C_DIM + lane * 4);
    const f4 wr = *reinterpret_cast<const f4*>(W + lane * 4);
    const f4 wc = *reinterpret_cast<const f4*>(W + C_DIM + lane * 4);

    float pr = xv.x * wr.x + xv.y * wr.y + xv.z * wr.z + xv.w * wr.w;
    float pc = xv.x * wc.x + xv.y * wc.y + xv.z * wc.z + xv.w * wc.w;

    #pragma unroll
    for (int off = 16; off > 0; off >>= 1) {
        pr += __shfl_down(pr, off, 32);
        pc += __shfl_down(pc, off, 32);
    }
    if (lane == 0) {
        g_s_row[node] = pr;
        g_s_col[node] = pc;
    }
}

// ---------------------------------------------------------------------------
// Fused kernel B+C (indices are INT32 — harness contract "integer -> int*";
// reading them as int64 was the cause of the previous memory-fault aborts):
//   sig(e) = sigmoid(g_s_row[ei[0][e]] + g_s_col[ei[1][e]])
//   out[e] = sig(e) * sig(lr[e])
// Partner sigmoid is RECOMPUTED instead of staging a wts[] table — saves the
// 6.4MB write + re-read round trip and one launch. Partner gathers are
// cache-absorbed: s-tables 800KB (L2-resident); ei re-reads hit L2/L3.
// Dead streams (lr in, out out) are non-temporal so they don't evict the
// 12.8MB ei working set. 4 edges/thread; 16B loads; E % 4 == 0 -> no tail.
// ---------------------------------------------------------------------------
__device__ __forceinline__ float sigmoid_of_edge(const int* __restrict__ ei, int e) {
    const int r = ei[e];
    const int c = ei[E_EDGES + e];
    const float s = g_s_row[r] + g_s_col[c];
    return 1.0f / (1.0f + expf(-s));
}

__global__ void edge_fused_kernel(const int* __restrict__ ei,
                                  const int* __restrict__ lr,
                                  float* __restrict__ out) {
    const int e = (blockIdx.x * blockDim.x + threadIdx.x) * 4;
    if (e >= E_EDGES) return;

    // Coalesced 16B index loads: own row/col indices (cached — ei is re-read
    // by partner gathers) and partner indices (non-temporal — read once).
    const i4 r4 = *reinterpret_cast<const i4*>(ei + e);
    const i4 c4 = *reinterpret_cast<const i4*>(ei + E_EDGES + e);
    const i4 l4 = __builtin_nontemporal_load(reinterpret_cast<const i4*>(lr + e));

    // Own scores.
    const float s0 = g_s_row[r4.x] + g_s_col[c4.x];
    const float s1 = g_s_row[r4.y] + g_s_col[c4.y];
    const float s2 = g_s_row[r4.z] + g_s_col[c4.z];
    const float s3 = g_s_row[r4.w] + g_s_col[c4.w];

    const float w0 = 1.0f / (1.0f + expf(-s0));
    const float w1 = 1.0f / (1.0f + expf(-s1));
    const float w2 = 1.0f / (1.0f + expf(-s2));
    const float w3 = 1.0f / (1.0f + expf(-s3));

    // Partner sigmoids (random path, cache-absorbed).
    const float p0 = sigmoid_of_edge(ei, l4.x);
    const float p1 = sigmoid_of_edge(ei, l4.y);
    const float p2 = sigmoid_of_edge(ei, l4.z);
    const float p3 = sigmoid_of_edge(ei, l4.w);

    // One 16B non-temporal result store (write-once, never re-read).
    f4 o;
    o.x = w0 * p0;
    o.y = w1 * p1;
    o.z = w2 * p2;
    o.w = w3 * p3;
    __builtin_nontemporal_store(o, reinterpret_cast<f4*>(out + e));
}

extern "C" void kernel_launch(void* const* d_in, const int* in_sizes, int n_in,
                              void* d_out, int out_size, void* d_ws, size_t ws_size,
                              hipStream_t stream) {
    const float* x  = (const float*)d_in[0];   // (N, C) f32
    const int*   ei = (const int*)d_in[1];     // (2, E) int32 (JAX x64 disabled)
    const int*   lr = (const int*)d_in[2];     // (E,)   int32
    const float* W  = (const float*)d_in[3];   // (1, 2C) f32
    float* out = (float*)d_out;                // (E,)   f32

    node_dots_kernel<<<(N_NODES + 7) / 8, 256, 0, stream>>>(x, W);

    const int threads_e = E_EDGES / 4;          // 400000
    edge_fused_kernel<<<(threads_e + 255) / 256, 256, 0, stream>>>(ei, lr, out);
}

// Round 15
// 133.225 us; speedup vs baseline: 1.2191x; 1.2191x over previous
//
#include <hip/hip_runtime.h>

#define N_NODES 100000
#define C_DIM   128
#define E_EDGES 1600000

// clang native vector types (accepted by __builtin_nontemporal_*).
typedef int   i4 __attribute__((ext_vector_type(4)));
typedef float f4 __attribute__((ext_vector_type(4)));

// Node-score tables in device globals (800 KB) — no ws_size assumption.
// Fully rewritten by node_dots_kernel every call before readers run
// (same-stream ordering) — no cross-call state dependence.
__device__ float g_s_row[N_NODES];
__device__ float g_s_col[N_NODES];

// ---------------------------------------------------------------------------
// Kernel A: per-node dot products with w_row (W[0:128]) and w_col (W[128:256]).
// 32 lanes per node, float4 per lane -> one coalesced 512B segment per node.
// 256 threads/block => 8 nodes/block. N=100000 -> 12500 blocks exactly.
// WATCH: R13 implies this kernel + overheads ≈ 90µs vs the 8µs traffic model —
// verify its standalone duration in the next profile.
// ---------------------------------------------------------------------------
__global__ void node_dots_kernel(const float* __restrict__ x,
                                 const float* __restrict__ W) {
    const int lane = threadIdx.x & 31;        // 0..31 within node
    const int node = blockIdx.x * 8 + (threadIdx.x >> 5);
    if (node >= N_NODES) return;

    const f4 xv = *reinterpret_cast<const f4*>(x + (size_t)node * C_DIM + lane * 4);
    const f4 wr = *reinterpret_cast<const f4*>(W + lane * 4);
    const f4 wc = *reinterpret_cast<const f4*>(W + C_DIM + lane * 4);

    float pr = xv.x * wr.x + xv.y * wr.y + xv.z * wr.z + xv.w * wr.w;
    float pc = xv.x * wc.x + xv.y * wc.y + xv.z * wc.z + xv.w * wc.w;

    #pragma unroll
    for (int off = 16; off > 0; off >>= 1) {
        pr += __shfl_down(pr, off, 32);
        pc += __shfl_down(pc, off, 32);
    }
    if (lane == 0) {
        g_s_row[node] = pr;
        g_s_col[node] = pc;
    }
}

// ---------------------------------------------------------------------------
// Kernel B: wts[e] = sigmoid(g_s_row[ei[0][e]] + g_s_col[ei[1][e]])
// REVERTED from partner-recompute to a staged wts table: Round-13 counters
// showed the recompute's random 4B reads into the 12.8MB ei array fetched
// 167MB from HBM (each gather drags a full cacheline). Staging wts makes the
// partner gather a single 4B read into a 6.4MB table that kernel C finds
// L2-resident (B writes it immediately before).
// ei is read ONCE, streamed -> non-temporal. s-table gathers stay cached
// (800KB, L2-resident). wts write is cacheable on purpose (C re-reads it).
// 4 edges/thread; 16B loads; E % 4 == 0 -> no tail.
// ---------------------------------------------------------------------------
__global__ void edge_sigmoid_kernel(const int* __restrict__ ei,
                                    float* __restrict__ wts) {
    const int e = (blockIdx.x * blockDim.x + threadIdx.x) * 4;
    if (e >= E_EDGES) return;

    const i4 r4 = __builtin_nontemporal_load(reinterpret_cast<const i4*>(ei + e));
    const i4 c4 = __builtin_nontemporal_load(reinterpret_cast<const i4*>(ei + E_EDGES + e));

    const float s0 = g_s_row[r4.x] + g_s_col[c4.x];
    const float s1 = g_s_row[r4.y] + g_s_col[c4.y];
    const float s2 = g_s_row[r4.z] + g_s_col[c4.z];
    const float s3 = g_s_row[r4.w] + g_s_col[c4.w];

    f4 w;
    w.x = 1.0f / (1.0f + expf(-s0));
    w.y = 1.0f / (1.0f + expf(-s1));
    w.z = 1.0f / (1.0f + expf(-s2));
    w.w = 1.0f / (1.0f + expf(-s3));
    *reinterpret_cast<f4*>(wts + e) = w;   // cacheable: kernel C gathers from it
}

// ---------------------------------------------------------------------------
// Kernel C: out[e] = wts[e] * wts[lr[e]]
// lr: read-once stream -> nt load. wts: stream + random gather into the same
// 6.4MB array -> cacheable (gather should hit L2 lines left by kernel B).
// out: write-once -> nt store.
// ---------------------------------------------------------------------------
__global__ void pair_mul_kernel(const float* __restrict__ wts,
                                const int* __restrict__ lr,
                                float* __restrict__ out) {
    const int e = (blockIdx.x * blockDim.x + threadIdx.x) * 4;
    if (e >= E_EDGES) return;

    const i4 l4 = __builtin_nontemporal_load(reinterpret_cast<const i4*>(lr + e));
    const f4 w4 = *reinterpret_cast<const f4*>(wts + e);

    f4 o;
    o.x = w4.x * wts[l4.x];
    o.y = w4.y * wts[l4.y];
    o.z = w4.z * wts[l4.z];
    o.w = w4.w * wts[l4.w];
    __builtin_nontemporal_store(o, reinterpret_cast<f4*>(out + e));
}

extern "C" void kernel_launch(void* const* d_in, const int* in_sizes, int n_in,
                              void* d_out, int out_size, void* d_ws, size_t ws_size,
                              hipStream_t stream) {
    const float* x  = (const float*)d_in[0];   // (N, C) f32
    const int*   ei = (const int*)d_in[1];     // (2, E) int32 (JAX x64 disabled)
    const int*   lr = (const int*)d_in[2];     // (E,)   int32
    const float* W  = (const float*)d_in[3];   // (1, 2C) f32
    float* out = (float*)d_out;                // (E,)   f32

    // wts table in d_ws (6.4 MB scratch).
    float* wts = (float*)d_ws;

    node_dots_kernel<<<(N_NODES + 7) / 8, 256, 0, stream>>>(x, W);

    const int threads_e = E_EDGES / 4;          // 400000 -> 1563 blocks
    edge_sigmoid_kernel<<<(threads_e + 255) / 256, 256, 0, stream>>>(ei, wts);
    pair_mul_kernel<<<(threads_e + 255) / 256, 256, 0, stream>>>(wts, lr, out);
}

// Round 18
// 130.650 us; speedup vs baseline: 1.2431x; 1.0197x over previous
//
#include <hip/hip_runtime.h>

#define N_NODES 100000
#define C_DIM   128
#define E_EDGES 1600000

// clang native vector types (accepted by __builtin_nontemporal_*).
typedef int   i4 __attribute__((ext_vector_type(4)));
typedef float f4 __attribute__((ext_vector_type(4)));

// Node-score tables in device globals (800 KB). Fully rewritten by
// node_dots_kernel every call before readers run (same-stream ordering).
__device__ float g_s_row[N_NODES];
__device__ float g_s_col[N_NODES];

// ---------------------------------------------------------------------------
// Kernel A: per-node dots with w_row (W[0:128]) / w_col (W[128:256]).
// R16 change: 16 lanes/node, TWO float4s per lane (32B) -> 2 independent
// loads in flight per thread (double the MLP of the 32-lane version), and a
// 4-step shuffle reduce instead of 5. 256 threads/block => 16 nodes/block;
// per 64-lane wave: 4 nodes x 512B = 2KB contiguous. 6250 blocks.
// ---------------------------------------------------------------------------
__global__ void node_dots_kernel(const float* __restrict__ x,
                                 const float* __restrict__ W) {
    const int lane = threadIdx.x & 15;               // 0..15 within node
    const int node = blockIdx.x * 16 + (threadIdx.x >> 4);
    if (node >= N_NODES) return;

    const float* xp = x + (size_t)node * C_DIM + lane * 8;
    const f4 xa = *reinterpret_cast<const f4*>(xp);
    const f4 xb = *reinterpret_cast<const f4*>(xp + 4);
    const f4 wra = *reinterpret_cast<const f4*>(W + lane * 8);
    const f4 wrb = *reinterpret_cast<const f4*>(W + lane * 8 + 4);
    const f4 wca = *reinterpret_cast<const f4*>(W + C_DIM + lane * 8);
    const f4 wcb = *reinterpret_cast<const f4*>(W + C_DIM + lane * 8 + 4);

    float pr = xa.x * wra.x + xa.y * wra.y + xa.z * wra.z + xa.w * wra.w
             + xb.x * wrb.x + xb.y * wrb.y + xb.z * wrb.z + xb.w * wrb.w;
    float pc = xa.x * wca.x + xa.y * wca.y + xa.z * wca.z + xa.w * wca.w
             + xb.x * wcb.x + xb.y * wcb.y + xb.z * wcb.z + xb.w * wcb.w;

    #pragma unroll
    for (int off = 8; off > 0; off >>= 1) {
        pr += __shfl_down(pr, off, 16);
        pc += __shfl_down(pc, off, 16);
    }
    if (lane == 0) {
        g_s_row[node] = pr;
        g_s_col[node] = pc;
    }
}

// ---------------------------------------------------------------------------
// Kernel B: wts[e] = sigmoid(g_s_row[ei[0][e]] + g_s_col[ei[1][e]])
// (R15-validated: staging wts beats partner-recompute — R13's recompute
// fetched 167MB HBM via random cacheline drags into ei.)
// ei: read-once stream -> nt. s-tables: 800KB, cache-resident gathers.
// wts write cacheable on purpose (kernel C re-reads it).
// ---------------------------------------------------------------------------
__global__ void edge_sigmoid_kernel(const int* __restrict__ ei,
                                    float* __restrict__ wts) {
    const int e = (blockIdx.x * blockDim.x + threadIdx.x) * 4;
    if (e >= E_EDGES) return;

    const i4 r4 = __builtin_nontemporal_load(reinterpret_cast<const i4*>(ei + e));
    const i4 c4 = __builtin_nontemporal_load(reinterpret_cast<const i4*>(ei + E_EDGES + e));

    const float s0 = g_s_row[r4.x] + g_s_col[c4.x];
    const float s1 = g_s_row[r4.y] + g_s_col[c4.y];
    const float s2 = g_s_row[r4.z] + g_s_col[c4.z];
    const float s3 = g_s_row[r4.w] + g_s_col[c4.w];

    f4 w;
    w.x = 1.0f / (1.0f + expf(-s0));
    w.y = 1.0f / (1.0f + expf(-s1));
    w.z = 1.0f / (1.0f + expf(-s2));
    w.w = 1.0f / (1.0f + expf(-s3));
    *reinterpret_cast<f4*>(wts + e) = w;
}

// ---------------------------------------------------------------------------
// Kernel C: out[e] = wts[e] * wts[lr[e]]
// lr: read-once -> nt. wts stream + random gather into 6.4MB (L2/L3 after
// B's kernel-end flush). out: write-once -> nt.
// ---------------------------------------------------------------------------
__global__ void pair_mul_kernel(const float* __restrict__ wts,
                                const int* __restrict__ lr,
                                float* __restrict__ out) {
    const int e = (blockIdx.x * blockDim.x + threadIdx.x) * 4;
    if (e >= E_EDGES) return;

    const i4 l4 = __builtin_nontemporal_load(reinterpret_cast<const i4*>(lr + e));
    const f4 w4 = *reinterpret_cast<const f4*>(wts + e);

    f4 o;
    o.x = w4.x * wts[l4.x];
    o.y = w4.y * wts[l4.y];
    o.z = w4.z * wts[l4.z];
    o.w = w4.w * wts[l4.w];
    __builtin_nontemporal_store(o, reinterpret_cast<f4*>(out + e));
}

extern "C" void kernel_launch(void* const* d_in, const int* in_sizes, int n_in,
                              void* d_out, int out_size, void* d_ws, size_t ws_size,
                              hipStream_t stream) {
    const float* x  = (const float*)d_in[0];   // (N, C) f32
    const int*   ei = (const int*)d_in[1];     // (2, E) int32 (JAX x64 disabled)
    const int*   lr = (const int*)d_in[2];     // (E,)   int32
    const float* W  = (const float*)d_in[3];   // (1, 2C) f32
    float* out = (float*)d_out;                // (E,)   f32

    float* wts = (float*)d_ws;                 // 6.4 MB scratch

    node_dots_kernel<<<(N_NODES + 15) / 16, 256, 0, stream>>>(x, W);

    const int threads_e = E_EDGES / 4;          // 400000 -> 1563 blocks
    edge_sigmoid_kernel<<<(threads_e + 255) / 256, 256, 0, stream>>>(ei, wts);
    pair_mul_kernel<<<(threads_e + 255) / 256, 256, 0, stream>>>(wts, lr, out);
}